// Round 25
// baseline (66.520 us; speedup 1.0000x reference)
//
#include <hip/hip_runtime.h>
#include <hip/hip_bf16.h>

typedef __bf16 bf16x4 __attribute__((ext_vector_type(4)));
typedef __bf16 bf16x8 __attribute__((ext_vector_type(8)));
typedef float  f32x4  __attribute__((ext_vector_type(4)));

#define IN_F   4096
#define OUT_F  4096
#define RANK   32

__device__ __forceinline__ bf16x8 cvt8(float4 a, float4 b) {
    bf16x8 r;
    r[0] = (__bf16)a.x; r[1] = (__bf16)a.y; r[2] = (__bf16)a.z; r[3] = (__bf16)a.w;
    r[4] = (__bf16)b.x; r[5] = (__bf16)b.y; r[6] = (__bf16)b.z; r[7] = (__bf16)b.w;
    return r;
}
__device__ __forceinline__ bf16x4 cvt4(float4 a) {
    bf16x4 r;
    r[0] = (__bf16)a.x; r[1] = (__bf16)a.y; r[2] = (__bf16)a.z; r[3] = (__bf16)a.w;
    return r;
}

// ---------------- Kernel 1: Hpart[slice] = X @ V^T (bf16 partials) ----------------
// R22's proven 4.8 TB/s structure x R17's minimal traffic: 2048 blocks
// ((128 token-blocks, 16 slices)), 256 thr (4 waves), (256,6) -> 6 blocks/CU,
// 24 waves/CU. Block = 64 tokens x 256 feats; V amortized over 64 tokens ->
// traffic = X 128 MB (once) + V 64 MB (L2-hot) = 192 MB. 4 chunks of 64
// feats, double-buffered bf16 LDS (24 KB), R22-proven XOR swizzle. Wave = tt,
// computes BOTH rank halves (acc[2], 4 MFMA/chunk). Stage = 6 loads/thread.
template <int KS>
__global__ __launch_bounds__(256, 6)
void lora_h(const float* __restrict__ X, const float* __restrict__ V,
            __hip_bfloat16* __restrict__ Hpart)
{
    constexpr int SL   = IN_F / KS;     // 256 feats per slice
    constexpr int NCHK = SL / 64;       // 4 chunks

    __shared__ __bf16 XL[2][64 * 64];   // 16 KB (double-buffered chunk)
    __shared__ __bf16 VL[2][32 * 64];   //  8 KB

    const int tid  = threadIdx.x;
    const int tt   = tid >> 6;          // wave = token 16-tile (0..3)
    const int lane = tid & 63;
    const int r    = lane & 15;
    const int kg   = lane >> 4;

    const int t0 = blockIdx.x * 64;
    const int f0 = blockIdx.y * SL;

    // stage chunk c (64 feats): X 4 + V 2 contiguous float4 loads/thread,
    // bf16-cvt, XOR-swizzled LDS write (R22-proven; <=2-way banks on read).
    auto stage = [&](int c, int buf) {
        const int fc = f0 + ((c + blockIdx.x) & (NCHK - 1)) * 64;
        #pragma unroll
        for (int i = 0; i < 4; ++i) {   // X: 1024 float4
            const int f4   = tid + i * 256;
            const int row  = f4 >> 4;
            const int colf = (f4 & 15) * 4;
            float4 xv = *reinterpret_cast<const float4*>(
                X + (size_t)(t0 + row) * IN_F + fc + colf);
            *reinterpret_cast<bf16x4*>(
                &XL[buf][row * 64 + (colf ^ ((row & 7) << 3))]) = cvt4(xv);
        }
        #pragma unroll
        for (int i = 0; i < 2; ++i) {   // V: 512 float4
            const int f4   = tid + i * 256;
            const int row  = f4 >> 4;   // 0..31
            const int colf = (f4 & 15) * 4;
            float4 vv = *reinterpret_cast<const float4*>(
                V + (size_t)row * IN_F + fc + colf);
            *reinterpret_cast<bf16x4*>(
                &VL[buf][row * 64 + (colf ^ ((row & 7) << 3))]) = cvt4(vv);
        }
    };

    f32x4 acc[2] = {};                  // rank halves for this wave's 16 tokens

    auto compute = [&](int buf) {
        const int sw = (r & 7) << 3;
        #pragma unroll
        for (int s = 0; s < 2; ++s) {   // 2 K-steps x 32 feats = 64
            bf16x8 xb = *reinterpret_cast<const bf16x8*>(
                &XL[buf][(tt * 16 + r) * 64 + ((s * 32 + kg * 8) ^ sw)]);
            #pragma unroll
            for (int rh = 0; rh < 2; ++rh) {
                bf16x8 vb = *reinterpret_cast<const bf16x8*>(
                    &VL[buf][(rh * 16 + r) * 64 + ((s * 32 + kg * 8) ^ sw)]);
                // A = X (m = token), B = V (n = rank-in-half)
                acc[rh] = __builtin_amdgcn_mfma_f32_16x16x32_bf16(xb, vb, acc[rh], 0, 0, 0);
            }
        }
    };

    stage(0, 0);
    __syncthreads();

    for (int c = 0; c < NCHK; ++c) {
        if (c + 1 < NCHK) stage(c + 1, (c + 1) & 1);  // other buffer: no race
        compute(c & 1);
        __syncthreads();                               // publish c+1, retire c
    }

    // D: token = t0 + tt*16 + kg*4 + j, rank = rh*16 + r. Direct bf16 store.
    __hip_bfloat16* Hq = Hpart + (size_t)blockIdx.y * (8192 * RANK)
                               + (size_t)(t0 + tt * 16) * RANK;
    #pragma unroll
    for (int j = 0; j < 4; ++j) {
        Hq[(size_t)(kg * 4 + j) * RANK + r]      = (__hip_bfloat16)acc[0][j];
        Hq[(size_t)(kg * 4 + j) * RANK + 16 + r] = (__hip_bfloat16)acc[1][j];
    }
}

// ---------------- Kernel 2 (fused reduce, ws path): Out = (sum Hpart)*S @ U^T ------
template <int NKS>
__global__ __launch_bounds__(256, 4)
void lora_out_f(const ushort* __restrict__ Hpart, const float* __restrict__ S,
                const float* __restrict__ U, float* __restrict__ Out)
{
    __shared__ float Hs[32][33];

    const int tid  = threadIdx.x;
    const int wave = tid >> 6;
    const int lane = tid & 63;
    const int r    = lane & 15;
    const int kg   = lane >> 4;

    const int tt = blockIdx.x >> 2;
    const int cq = blockIdx.x & 3;
    const int t0 = tt * 32;

    {   // reduce NKS bf16 slice-partials for this 32x32 H tile, apply S
        const int rk = (tid & 7) * 4;
        float a0 = 0.f, a1 = 0.f, a2 = 0.f, a3 = 0.f;
        #pragma unroll
        for (int k = 0; k < NKS; ++k) {
            ushort4 u = *reinterpret_cast<const ushort4*>(
                Hpart + (size_t)k * (8192 * RANK) + (size_t)t0 * RANK + tid * 4);
            a0 += __uint_as_float((unsigned)u.x << 16);
            a1 += __uint_as_float((unsigned)u.y << 16);
            a2 += __uint_as_float((unsigned)u.z << 16);
            a3 += __uint_as_float((unsigned)u.w << 16);
        }
        const int tok = tid >> 3;
        Hs[tok][rk]     = a0 * S[rk];
        Hs[tok][rk + 1] = a1 * S[rk + 1];
        Hs[tok][rk + 2] = a2 * S[rk + 2];
        Hs[tok][rk + 3] = a3 * S[rk + 3];
    }
    __syncthreads();

    bf16x8 hb[2];
    #pragma unroll
    for (int a = 0; a < 2; ++a)
        #pragma unroll
        for (int j = 0; j < 8; ++j) hb[a][j] = (__bf16)Hs[a * 16 + r][kg * 8 + j];

    const int wc0 = cq * 1024 + wave * 256;

    #pragma unroll
    for (int g = 0; g < 4; ++g) {
        float4 u0[4], u1[4];
        #pragma unroll
        for (int b = 0; b < 4; ++b) {
            const float4* up = reinterpret_cast<const float4*>(
                U + (size_t)(wc0 + g * 64 + b * 16 + r) * RANK + kg * 8);
            u0[b] = up[0];
            u1[b] = up[1];
        }
        #pragma unroll
        for (int b = 0; b < 4; ++b) {
            bf16x8 ub = cvt8(u0[b], u1[b]);
            #pragma unroll
            for (int a = 0; a < 2; ++a) {
                f32x4 d = {0.f, 0.f, 0.f, 0.f};
                d = __builtin_amdgcn_mfma_f32_16x16x32_bf16(ub, hb[a], d, 0, 0, 0);
                *reinterpret_cast<float4*>(
                    Out + (size_t)(t0 + a * 16 + r) * OUT_F
                        + wc0 + g * 64 + b * 16 + kg * 4)
                    = *reinterpret_cast<float4*>(&d);
            }
        }
    }
}

// ---------------- Fallback path: separate hred + K2-from-H (R23-proven) ----------
template <int NKS>
__global__ __launch_bounds__(256)
void lora_hred(const ushort* __restrict__ Hpart, const float* __restrict__ S,
               float* __restrict__ H)
{
    const int idx = (blockIdx.x * 256 + threadIdx.x) * 4;
    const int rk  = idx & 31;
    float acc[4] = {0.f, 0.f, 0.f, 0.f};
    #pragma unroll
    for (int k = 0; k < NKS; ++k) {
        ushort4 u = *reinterpret_cast<const ushort4*>(
            Hpart + (size_t)k * (8192 * RANK) + idx);
        acc[0] += __uint_as_float((unsigned)u.x << 16);
        acc[1] += __uint_as_float((unsigned)u.y << 16);
        acc[2] += __uint_as_float((unsigned)u.z << 16);
        acc[3] += __uint_as_float((unsigned)u.w << 16);
    }
    float4 out;
    out.x = acc[0] * S[rk];     out.y = acc[1] * S[rk + 1];
    out.z = acc[2] * S[rk + 2]; out.w = acc[3] * S[rk + 3];
    *reinterpret_cast<float4*>(H + idx) = out;
}

__global__ __launch_bounds__(256, 4)
void lora_out_h(const float* __restrict__ H, const float* __restrict__ U,
                float* __restrict__ Out)
{
    __shared__ float Hs[32][33];

    const int tid  = threadIdx.x;
    const int wave = tid >> 6;
    const int lane = tid & 63;
    const int r    = lane & 15;
    const int kg   = lane >> 4;

    const int tt = blockIdx.x >> 2;
    const int cq = blockIdx.x & 3;
    const int t0 = tt * 32;

    {
        float4 v = reinterpret_cast<const float4*>(H + (size_t)t0 * RANK)[tid];
        const int tok = tid >> 3;
        const int rr  = (tid & 7) * 4;
        Hs[tok][rr] = v.x; Hs[tok][rr + 1] = v.y;
        Hs[tok][rr + 2] = v.z; Hs[tok][rr + 3] = v.w;
    }
    __syncthreads();

    bf16x8 hb[2];
    #pragma unroll
    for (int a = 0; a < 2; ++a)
        #pragma unroll
        for (int j = 0; j < 8; ++j) hb[a][j] = (__bf16)Hs[a * 16 + r][kg * 8 + j];

    const int wc0 = cq * 1024 + wave * 256;

    #pragma unroll
    for (int g = 0; g < 4; ++g) {
        float4 u0[4], u1[4];
        #pragma unroll
        for (int b = 0; b < 4; ++b) {
            const float4* up = reinterpret_cast<const float4*>(
                U + (size_t)(wc0 + g * 64 + b * 16 + r) * RANK + kg * 8);
            u0[b] = up[0];
            u1[b] = up[1];
        }
        #pragma unroll
        for (int b = 0; b < 4; ++b) {
            bf16x8 ub = cvt8(u0[b], u1[b]);
            #pragma unroll
            for (int a = 0; a < 2; ++a) {
                f32x4 d = {0.f, 0.f, 0.f, 0.f};
                d = __builtin_amdgcn_mfma_f32_16x16x32_bf16(ub, hb[a], d, 0, 0, 0);
                *reinterpret_cast<float4*>(
                    Out + (size_t)(t0 + a * 16 + r) * OUT_F
                        + wc0 + g * 64 + b * 16 + kg * 4)
                    = *reinterpret_cast<float4*>(&d);
            }
        }
    }
}

extern "C" void kernel_launch(void* const* d_in, const int* in_sizes, int n_in,
                              void* d_out, int out_size, void* d_ws, size_t ws_size,
                              hipStream_t stream) {
    const float* X = (const float*)d_in[0];
    const float* U = (const float*)d_in[1];
    const float* S = (const float*)d_in[2];
    const float* V = (const float*)d_in[3];
    float* Out = (float*)d_out;

    if (ws_size >= (size_t)9 * 1024 * 1024) {
        // Hpart (16 slices bf16 = 8 MB) in d_ws; fused-reduce K2 (no race).
        __hip_bfloat16* Hpart = (__hip_bfloat16*)d_ws;
        lora_h<16><<<dim3(128, 16), 256, 0, stream>>>(X, V, Hpart);
        lora_out_f<16><<<1024, 256, 0, stream>>>((const ushort*)Hpart, S, U, Out);
    } else {
        // Hpart in d_out scratch (R23-proven): separate hred -> H in ws,
        // then K2 reads H and overwrites all of d_out.
        __hip_bfloat16* Hpart = (__hip_bfloat16*)d_out;
        float* H = (float*)d_ws;        // 1 MB
        lora_h<16><<<dim3(128, 16), 256, 0, stream>>>(X, V, Hpart);
        lora_hred<16><<<256, 256, 0, stream>>>((const ushort*)Hpart, S, H);
        lora_out_h<<<1024, 256, 0, stream>>>(H, U, Out);
    }
}

// Round 26
// 60.154 us; speedup vs baseline: 1.1058x; 1.1058x over previous
//
#include <hip/hip_runtime.h>
#include <hip/hip_bf16.h>

typedef __bf16 bf16x8 __attribute__((ext_vector_type(8)));
typedef float  f32x4  __attribute__((ext_vector_type(4)));

#define IN_F   4096
#define OUT_F  4096
#define RANK   32

__device__ __forceinline__ bf16x8 cvt8(float4 a, float4 b) {
    bf16x8 r;
    r[0] = (__bf16)a.x; r[1] = (__bf16)a.y; r[2] = (__bf16)a.z; r[3] = (__bf16)a.w;
    r[4] = (__bf16)b.x; r[5] = (__bf16)b.y; r[6] = (__bf16)b.z; r[7] = (__bf16)b.w;
    return r;
}

__device__ __forceinline__ void gl_lds16(const float* g, void* l) {
    __builtin_amdgcn_global_load_lds(
        (const __attribute__((address_space(1))) char*)g,
        (__attribute__((address_space(3))) char*)l, 16, 0, 0);
}

// ---------------- Kernel 1 (R17 verbatim — best measured K1, 51.8 µs) ----------------
// Hpart[ks] = (X @ V^T) * S over k-quarter. grid (128, KS), 512 thr (8 waves),
// 2 blocks/CU (72 KB LDS), triple-buffered 64-feat chunks, contiguous 1 KB
// gl_lds staging with XOR-swizzled sources, counted vmcnt, raw s_barrier.
template <int KS>
__global__ __launch_bounds__(512, 4)
void lora_h(const float* __restrict__ X, const float* __restrict__ S,
            const float* __restrict__ V, float* __restrict__ Hpart)
{
    constexpr int F    = IN_F / KS;
    constexpr int NCHK = F / 64;        // 64-feat chunks

    __shared__ float XL[3][64 * 64];    // [buf][row*64+col] 48 KB
    __shared__ float VL[3][32 * 64];    // [buf][row*64+col] 24 KB

    const int tid  = threadIdx.x;
    const int wave = tid >> 6;          // 0..7
    const int lane = tid & 63;
    const int r    = lane & 15;
    const int kg   = lane >> 4;

    const int tt = wave & 3;            // token 16-tile
    const int rh = wave >> 2;           // rank half

    const int t0    = blockIdx.x * 64;
    const int fbase = blockIdx.y * F;

    const float sr = S[rh * 16 + r];

    const int srow = lane >> 4;         // lane's row within each 4-row span
    const int scol = (lane & 15) * 4;   // lane's float col (0..60)

    // stage chunk c into buffer nb: 24 contiguous-1KB instructions, 3/wave
    auto stage = [&](int c, int nb) {
        const int fc = fbase + ((c + blockIdx.x) & (NCHK - 1)) * 64;
        #pragma unroll
        for (int t = 0; t < 3; ++t) {
            const int inst = wave * 3 + t;
            if (inst < 16) {            // X: instr i covers rows 4i..4i+3
                const int row = inst * 4 + srow;
                const int col = scol ^ ((row & 7) << 2);   // pre-swizzle
                gl_lds16(X + (size_t)(t0 + row) * IN_F + fc + col,
                         (void*)&XL[nb][inst * 256]);
            } else {                    // V: instr j covers rows 4j..4j+3
                const int j   = inst - 16;
                const int row = j * 4 + srow;
                const int col = scol ^ ((row & 7) << 2);
                gl_lds16(V + (size_t)row * IN_F + fc + col,
                         (void*)&VL[nb][j * 256]);
            }
        }
    };

    f32x4 acc = {0.f, 0.f, 0.f, 0.f};   // this wave's (tt, rh) 16x16 tile

    auto compute = [&](int cur) {
        const int sw = (r & 7) << 2;    // read-side swizzle (matches source)
        const int xrow = (tt * 16 + r) * 64;
        const int vrow = (rh * 16 + r) * 64;
        #pragma unroll
        for (int s = 0; s < 2; ++s) {
            const int base = s * 32 + kg * 8;
            float4 x0 = *(const float4*)&XL[cur][xrow + ((base)     ^ sw)];
            float4 x1 = *(const float4*)&XL[cur][xrow + ((base + 4) ^ sw)];
            float4 v0 = *(const float4*)&VL[cur][vrow + ((base)     ^ sw)];
            float4 v1 = *(const float4*)&VL[cur][vrow + ((base + 4) ^ sw)];
            // A = X (m = token), B = V (n = rank-in-half)
            acc = __builtin_amdgcn_mfma_f32_16x16x32_bf16(
                      cvt8(x0, x1), cvt8(v0, v1), acc, 0, 0, 0);
        }
    };

    stage(0, 0);
    stage(1, 1);

    for (int c = 0; c < NCHK; ++c) {
        if (c + 2 < NCHK) {
            stage(c + 2, (c + 2) % 3);
            asm volatile("s_waitcnt vmcnt(6)" ::: "memory");  // chunk c landed; c+1,c+2 in flight
        } else if (c + 1 < NCHK) {
            asm volatile("s_waitcnt vmcnt(3)" ::: "memory");
        } else {
            asm volatile("s_waitcnt vmcnt(0)" ::: "memory");
        }
        __builtin_amdgcn_s_barrier();
        __builtin_amdgcn_sched_barrier(0);
        compute(c % 3);
        __builtin_amdgcn_s_barrier();   // readers done before buf re-staged
    }

    // D: token = tt*16 + kg*4 + j, rank = rh*16 + r. Direct global store.
    float* Hq = Hpart + ((size_t)blockIdx.y * 8192 + t0) * RANK;
    #pragma unroll
    for (int j = 0; j < 4; ++j) {
        const int tok = tt * 16 + kg * 4 + j;
        Hq[(size_t)tok * RANK + rh * 16 + r] = acc[j] * sr;
    }
}

// ---------------- Kernel 2: Out = (sum_k Hpart[k]) @ U^T  (reduce fused) ----------------
// grid 1024, 256 thr. Block: 32 tokens x 1024 cols; each thread reduces the
// NKS fp32 partials for its float4 of the H tile inline (L3-resident, +12 MB),
// then the proven fast-K2 body: sequential U stream, 1 KB contiguous write
// bursts per row per wave. Saves the separate hred dispatch (~2.5 µs).
template <int NKS>
__global__ __launch_bounds__(256, 4)
void lora_out(const float* __restrict__ Hpart, const float* __restrict__ U,
              float* __restrict__ Out)
{
    __shared__ float Hs[32][33];

    const int tid  = threadIdx.x;
    const int wave = tid >> 6;
    const int lane = tid & 63;
    const int r    = lane & 15;
    const int kg   = lane >> 4;

    const int tt = blockIdx.x >> 2;
    const int cq = blockIdx.x & 3;
    const int t0 = tt * 32;

    {
        float4 v = {0.f, 0.f, 0.f, 0.f};
        #pragma unroll
        for (int k = 0; k < NKS; ++k) {
            float4 p = reinterpret_cast<const float4*>(
                Hpart + (size_t)k * (8192 * RANK) + (size_t)t0 * RANK)[tid];
            v.x += p.x; v.y += p.y; v.z += p.z; v.w += p.w;
        }
        const int tok = tid >> 3;
        const int rr  = (tid & 7) * 4;
        Hs[tok][rr] = v.x; Hs[tok][rr + 1] = v.y;
        Hs[tok][rr + 2] = v.z; Hs[tok][rr + 3] = v.w;
    }
    __syncthreads();

    bf16x8 hb[2];
    #pragma unroll
    for (int a = 0; a < 2; ++a)
        #pragma unroll
        for (int j = 0; j < 8; ++j) hb[a][j] = (__bf16)Hs[a * 16 + r][kg * 8 + j];

    const int wc0 = cq * 1024 + wave * 256;

    #pragma unroll
    for (int g = 0; g < 4; ++g) {
        float4 u0[4], u1[4];
        #pragma unroll
        for (int b = 0; b < 4; ++b) {
            const float4* up = reinterpret_cast<const float4*>(
                U + (size_t)(wc0 + g * 64 + b * 16 + r) * RANK + kg * 8);
            u0[b] = up[0];
            u1[b] = up[1];
        }
        #pragma unroll
        for (int b = 0; b < 4; ++b) {
            bf16x8 ub = cvt8(u0[b], u1[b]);
            #pragma unroll
            for (int a = 0; a < 2; ++a) {
                f32x4 d = {0.f, 0.f, 0.f, 0.f};
                d = __builtin_amdgcn_mfma_f32_16x16x32_bf16(ub, hb[a], d, 0, 0, 0);
                *reinterpret_cast<float4*>(
                    Out + (size_t)(t0 + a * 16 + r) * OUT_F
                        + wc0 + g * 64 + b * 16 + kg * 4)
                    = *reinterpret_cast<float4*>(&d);
            }
        }
    }
}

extern "C" void kernel_launch(void* const* d_in, const int* in_sizes, int n_in,
                              void* d_out, int out_size, void* d_ws, size_t ws_size,
                              hipStream_t stream) {
    const float* X = (const float*)d_in[0];
    const float* U = (const float*)d_in[1];
    const float* S = (const float*)d_in[2];
    const float* V = (const float*)d_in[3];
    float* Out = (float*)d_out;

    float* Hpart = (float*)d_ws;        // 4 MB fp32 partials (KS=4)

    if (ws_size >= (size_t)4 * 1024 * 1024) {
        lora_h<4><<<dim3(128, 4), 512, 0, stream>>>(X, S, V, Hpart);
        lora_out<4><<<1024, 256, 0, stream>>>(Hpart, U, Out);
    } else {
        lora_h<1><<<dim3(128, 1), 512, 0, stream>>>(X, S, V, Hpart);
        lora_out<1><<<1024, 256, 0, stream>>>(Hpart, U, Out);
    }
}